// Round 9
// baseline (2834.039 us; speedup 1.0000x reference)
//
#include <hip/hip_runtime.h>
#include <cmath>

#define NROWS 32768
#define HID   1024
#define DIM   128
#define KCODE 4096
#define QBLK  384   // OpenBLAS sgemm kc (validated round 4): folds at 384,768,1024

typedef __attribute__((ext_vector_type(8))) short short8;
typedef __attribute__((ext_vector_type(4))) float f32x4;

// ---------------------------------------------------------------------------
// Encoder layer 1 (bit-exact, validated)
// ---------------------------------------------------------------------------
__global__ __launch_bounds__(256) void enc1_kernel(const float* __restrict__ act,
                                                   const float* __restrict__ W1,
                                                   const float* __restrict__ b1,
                                                   float* __restrict__ h1)
{
    const int h = blockIdx.x * 256 + threadIdx.x;
    const int n = blockIdx.y;
    float a0 = act[n*6+0], a1 = act[n*6+1], a2 = act[n*6+2];
    float a3 = act[n*6+3], a4 = act[n*6+4], a5 = act[n*6+5];
    float acc = 0.f;
    acc = fmaf(a0, W1[0*HID + h], acc);
    acc = fmaf(a1, W1[1*HID + h], acc);
    acc = fmaf(a2, W1[2*HID + h], acc);
    acc = fmaf(a3, W1[3*HID + h], acc);
    acc = fmaf(a4, W1[4*HID + h], acc);
    acc = fmaf(a5, W1[5*HID + h], acc);
    acc = __fadd_rn(acc, b1[h]);
    h1[(size_t)n*HID + h] = fmaxf(acc, 0.f);
}

// ---------------------------------------------------------------------------
// fp32 GEMM, bit-exact k-chain (sequential k, QBLK folds) — 8x8 micro-tile.
// 128x128 tile, BK=32, 256 thr. Thread (tx,ty):
//   rows {4ty+r, 64+4ty+r}, cols {4tx+j, 64+4tx+j}  (2x2 blocks of 4x4)
// 64 FMA per 4 ds_read_b128 (was 32 per 3).
// ---------------------------------------------------------------------------
template<int ACT>
__global__ __launch_bounds__(256, 2) void gemm8_kernel(const float* __restrict__ A,
                                                       const float* __restrict__ B,
                                                       const float* __restrict__ bias,
                                                       float* __restrict__ C,
                                                       int M, int K, int Nn)
{
    const int tid = threadIdx.x;
    const int tx = tid & 15, ty = tid >> 4;
    const int bn = blockIdx.x * 128;
    const int bm = blockIdx.y * 128;

    __shared__ float As[32][132];   // k-major; stride 132*4B, %128B = 16B-mult
    __shared__ float Bs[32][132];

    float accB[8][8];   // current kc-block chain
    float accC[8][8];   // folded total
    #pragma unroll
    for (int i = 0; i < 8; ++i)
        #pragma unroll
        for (int j = 0; j < 8; ++j) { accB[i][j] = 0.f; accC[i][j] = 0.f; }

    for (int kt = 0; kt < K; kt += 32) {
        #pragma unroll
        for (int p = 0; p < 4; ++p) {
            int idx = tid + p*256;
            int row = idx >> 3;
            int k4  = (idx & 7) * 4;
            const float4 v = *reinterpret_cast<const float4*>(&A[(size_t)(bm+row)*K + kt + k4]);
            As[k4+0][row] = v.x; As[k4+1][row] = v.y;
            As[k4+2][row] = v.z; As[k4+3][row] = v.w;
        }
        #pragma unroll
        for (int p = 0; p < 4; ++p) {
            int idx  = tid + p*256;
            int krow = idx >> 5;
            int n4   = (idx & 31) * 4;
            *reinterpret_cast<float4*>(&Bs[krow][n4]) =
                *reinterpret_cast<const float4*>(&B[(size_t)(kt+krow)*Nn + bn + n4]);
        }
        __syncthreads();
        #pragma unroll
        for (int kk = 0; kk < 32; ++kk) {
            const float4 a0 = *reinterpret_cast<const float4*>(&As[kk][4*ty]);
            const float4 a1 = *reinterpret_cast<const float4*>(&As[kk][4*ty + 64]);
            const float4 b0 = *reinterpret_cast<const float4*>(&Bs[kk][4*tx]);
            const float4 b1 = *reinterpret_cast<const float4*>(&Bs[kk][4*tx + 64]);
            const float aa[8] = {a0.x,a0.y,a0.z,a0.w,a1.x,a1.y,a1.z,a1.w};
            const float bb[8] = {b0.x,b0.y,b0.z,b0.w,b1.x,b1.y,b1.z,b1.w};
            #pragma unroll
            for (int r = 0; r < 8; ++r)
                #pragma unroll
                for (int j = 0; j < 8; ++j)
                    accB[r][j] = fmaf(aa[r], bb[j], accB[r][j]);
        }
        __syncthreads();
        // kc-block boundary: fold rounded partial (OpenBLAS beta-accumulate)
        if ((((kt + 32) % QBLK) == 0) || (kt + 32 >= K)) {
            #pragma unroll
            for (int i = 0; i < 8; ++i)
                #pragma unroll
                for (int j = 0; j < 8; ++j) {
                    accC[i][j] = __fadd_rn(accC[i][j], accB[i][j]);
                    accB[i][j] = 0.f;
                }
        }
    }
    const float4 bv0 = *reinterpret_cast<const float4*>(&bias[bn + 4*tx]);
    const float4 bv1 = *reinterpret_cast<const float4*>(&bias[bn + 4*tx + 64]);
    const float bb[8] = {bv0.x,bv0.y,bv0.z,bv0.w,bv1.x,bv1.y,bv1.z,bv1.w};
    #pragma unroll
    for (int gr = 0; gr < 2; ++gr)
        #pragma unroll
        for (int r = 0; r < 4; ++r) {
            const int i = gr*4 + r;
            const int row = bm + 64*gr + 4*ty + r;
            float o[8];
            #pragma unroll
            for (int j = 0; j < 8; ++j) {
                float v = __fadd_rn(accB[0][0]*0.f + accC[i][j], bb[j]);
                if (ACT == 1) v = fmaxf(v, 0.f);
                o[j] = v;
            }
            *reinterpret_cast<float4*>(&C[(size_t)row*Nn + bn + 4*tx])      = make_float4(o[0],o[1],o[2],o[3]);
            *reinterpret_cast<float4*>(&C[(size_t)row*Nn + bn + 64 + 4*tx]) = make_float4(o[4],o[5],o[6],o[7]);
        }
}

// ---------------------------------------------------------------------------
// bf16 split helpers (RNE); finite inputs only
// ---------------------------------------------------------------------------
__device__ inline unsigned short bf16_rne(float x) {
    union { float f; unsigned u; } a; a.f = x;
    unsigned r = a.u + 0x7FFFu + ((a.u >> 16) & 1u);
    return (unsigned short)(r >> 16);
}
__device__ inline void split_bf16(float x, unsigned short& hi, unsigned short& lo) {
    hi = bf16_rne(x);
    union { unsigned u; float f; } h; h.u = (unsigned)hi << 16;
    lo = bf16_rne(x - h.f);
}

// A [M][K] fp32 -> A' [M][3K] bf16 = [hi | hi | lo]
__global__ __launch_bounds__(256) void convA_kernel(const float* __restrict__ src,
                                                    unsigned short* __restrict__ dst,
                                                    int M, int K)
{
    const int kq = K >> 2;
    const int total = M * kq;
    for (int t = blockIdx.x*256 + threadIdx.x; t < total; t += gridDim.x*256) {
        int m  = t / kq;
        int kc = (t - m*kq) << 2;
        float4 v = *reinterpret_cast<const float4*>(&src[(size_t)m*K + kc]);
        ushort4 hi, lo;
        split_bf16(v.x, hi.x, lo.x);
        split_bf16(v.y, hi.y, lo.y);
        split_bf16(v.z, hi.z, lo.z);
        split_bf16(v.w, hi.w, lo.w);
        size_t base = (size_t)m*3*K;
        *reinterpret_cast<ushort4*>(&dst[base + kc])       = hi;
        *reinterpret_cast<ushort4*>(&dst[base + K + kc])   = hi;
        *reinterpret_cast<ushort4*>(&dst[base + 2*K + kc]) = lo;
    }
}

// W [K][N] fp32 -> W'T [N][3K] bf16 rows = [hi | lo | hi] (matches A' cols)
__global__ __launch_bounds__(256) void convW_kernel(const float* __restrict__ W,
                                                    unsigned short* __restrict__ WT,
                                                    int K, int N)
{
    const int total = K * N;
    for (int t = blockIdx.x*256 + threadIdx.x; t < total; t += gridDim.x*256) {
        int k = t / N, n = t - k*N;
        unsigned short hi, lo;
        split_bf16(W[(size_t)k*N + n], hi, lo);
        size_t base = (size_t)n*3*K;
        WT[base + k]       = hi;
        WT[base + K + k]   = lo;
        WT[base + 2*K + k] = hi;
    }
}

// ---------------------------------------------------------------------------
// bf16 MFMA GEMM (validated round 8 — UNCHANGED)
// ---------------------------------------------------------------------------
template<int ACT>
__global__ __launch_bounds__(256) void gemm_bf16_kernel(const unsigned short* __restrict__ A,
                                                        const unsigned short* __restrict__ BT,
                                                        const float* __restrict__ bias,
                                                        float* __restrict__ C,
                                                        int M, int Kp, int Nn)
{
    __shared__ unsigned short Asm[128*64];
    __shared__ unsigned short Bsm[128*64];
    const int tid  = threadIdx.x;
    const int lane = tid & 63;
    const int wave = tid >> 6;
    const int wr = wave >> 1, wc = wave & 1;
    const int bm = blockIdx.y * 128, bn = blockIdx.x * 128;
    const int l15 = lane & 15, l4 = lane >> 4;

    f32x4 acc[4][4];
    #pragma unroll
    for (int i = 0; i < 4; ++i)
        #pragma unroll
        for (int j = 0; j < 4; ++j) acc[i][j] = (f32x4){0.f,0.f,0.f,0.f};

    const int srow = tid >> 3;
    const int sch  = (tid & 7) * 8;
    for (int kt = 0; kt < Kp; kt += 64) {
        #pragma unroll
        for (int p = 0; p < 4; ++p) {
            int row = srow + 32*p;
            short8 va = *reinterpret_cast<const short8*>(&A[(size_t)(bm+row)*Kp + kt + sch]);
            short8 vb = *reinterpret_cast<const short8*>(&BT[(size_t)(bn+row)*Kp + kt + sch]);
            int byte = (row*128 + sch*2) ^ ((row & 7) << 4);
            *reinterpret_cast<short8*>((char*)Asm + byte) = va;
            *reinterpret_cast<short8*>((char*)Bsm + byte) = vb;
        }
        __syncthreads();
        #pragma unroll
        for (int ks = 0; ks < 64; ks += 32) {
            const int kk2 = (ks + l4*8) * 2;
            short8 af[4], bf[4];
            #pragma unroll
            for (int i = 0; i < 4; ++i) {
                int mrow = wr*64 + i*16 + l15;
                af[i] = *reinterpret_cast<const short8*>((char*)Asm + ((mrow*128 + kk2) ^ ((mrow & 7) << 4)));
                int nrow = wc*64 + i*16 + l15;
                bf[i] = *reinterpret_cast<const short8*>((char*)Bsm + ((nrow*128 + kk2) ^ ((nrow & 7) << 4)));
            }
            #pragma unroll
            for (int i = 0; i < 4; ++i)
                #pragma unroll
                for (int j = 0; j < 4; ++j)
                    acc[i][j] = __builtin_amdgcn_mfma_f32_16x16x32_bf16(af[i], bf[j], acc[i][j], 0, 0, 0);
        }
        __syncthreads();
    }
    #pragma unroll
    for (int j = 0; j < 4; ++j) {
        const int col = bn + wc*64 + j*16 + l15;
        const float bv = bias[col];
        #pragma unroll
        for (int i = 0; i < 4; ++i) {
            #pragma unroll
            for (int r = 0; r < 4; ++r) {
                const int row = bm + wr*64 + i*16 + l4*4 + r;
                float v = acc[i][j][r] + bv;
                if (ACT == 1) v = fmaxf(v, 0.f);
                C[(size_t)row*Nn + col] = v;
            }
        }
    }
}

// ---------------------------------------------------------------------------
// numpy pairwise row-norm (validated bit-exact)
// ---------------------------------------------------------------------------
__global__ __launch_bounds__(128) void rownorm_np_kernel(const float* __restrict__ X,
                                                         int nrows,
                                                         float* __restrict__ out)
{
    const int r = blockIdx.x * 128 + threadIdx.x;
    if (r >= nrows) return;
    const float* p = X + (size_t)r * DIM;
    float lane[16];
    #pragma unroll
    for (int l = 0; l < 16; ++l) {
        float x0 = p[0*16 + l],  y0 = p[64 + 0*16 + l];
        float x1 = p[1*16 + l],  y1 = p[64 + 1*16 + l];
        float a0 = __fadd_rn(__fmul_rn(x0, x0), __fmul_rn(y0, y0));
        float a1 = __fadd_rn(__fmul_rn(x1, x1), __fmul_rn(y1, y1));
        float r01 = __fadd_rn(a0, a1);
        float x2 = p[2*16 + l],  y2 = p[64 + 2*16 + l];
        float x3 = p[3*16 + l],  y3 = p[64 + 3*16 + l];
        float a2 = __fadd_rn(__fmul_rn(x2, x2), __fmul_rn(y2, y2));
        float a3 = __fadd_rn(__fmul_rn(x3, x3), __fmul_rn(y3, y3));
        float r23 = __fadd_rn(a2, a3);
        lane[l] = __fadd_rn(r01, r23);
    }
    float s[8];
    #pragma unroll
    for (int l = 0; l < 8; ++l) s[l] = __fadd_rn(lane[l], lane[l+8]);
    float u[4];
    #pragma unroll
    for (int l = 0; l < 4; ++l) u[l] = __fadd_rn(s[l], s[l+4]);
    float v0 = __fadd_rn(u[0], u[2]);
    float v1 = __fadd_rn(u[1], u[3]);
    out[r] = __fadd_rn(v0, v1);
}

// ---------------------------------------------------------------------------
// Fused VQ — 8x8 micro: 128 rows/block x 128 codes/tile, 256 blocks.
// dist = fl( fl(SL+CN) - 2P ), P = sequential-d fmaf chain (bit-exact).
// Rows {4ty+r, 64+4ty+r}; codes {4tx+j, 64+4tx+j}; argmin shfl over tx,
// first-index tie-break (semantics identical to validated round 7).
// ---------------------------------------------------------------------------
__global__ __launch_bounds__(256, 2) void vq_kernel(const float* __restrict__ L,
                                                    const float* __restrict__ CB,
                                                    const float* __restrict__ SL,
                                                    const float* __restrict__ CN,
                                                    float* __restrict__ outInd,
                                                    float* __restrict__ outQ,
                                                    float* __restrict__ lossAcc)
{
    const int tid = threadIdx.x;
    const int tx = tid & 15, ty = tid >> 4;
    const int bm = blockIdx.x * 128;

    __shared__ float As[32][132];   // [d][row]
    __shared__ float Bs[32][132];   // [d][code]
    __shared__ int   sIdx[128];

    float slr[8], bestv[8];
    int   besti[8];
    #pragma unroll
    for (int gr = 0; gr < 2; ++gr)
        #pragma unroll
        for (int r = 0; r < 4; ++r) {
            slr[gr*4+r] = SL[bm + 64*gr + 4*ty + r];
            bestv[gr*4+r] = 3.4e38f; besti[gr*4+r] = 0x7fffffff;
        }

    for (int k0 = 0; k0 < KCODE; k0 += 128) {
        float acc[8][8];
        #pragma unroll
        for (int r = 0; r < 8; ++r)
            #pragma unroll
            for (int j = 0; j < 8; ++j) acc[r][j] = 0.f;

        for (int d0 = 0; d0 < DIM; d0 += 32) {
            #pragma unroll
            for (int p = 0; p < 4; ++p) {
                int idx = tid + p*256;
                int row = idx >> 3;
                int d4  = (idx & 7) * 4;
                const float4 v = *reinterpret_cast<const float4*>(&L[(size_t)(bm+row)*DIM + d0 + d4]);
                As[d4+0][row] = v.x; As[d4+1][row] = v.y;
                As[d4+2][row] = v.z; As[d4+3][row] = v.w;
                const float4 w = *reinterpret_cast<const float4*>(&CB[(size_t)(k0+row)*DIM + d0 + d4]);
                Bs[d4+0][row] = w.x; Bs[d4+1][row] = w.y;
                Bs[d4+2][row] = w.z; Bs[d4+3][row] = w.w;
            }
            __syncthreads();
            #pragma unroll
            for (int dd = 0; dd < 32; ++dd) {
                const float4 a0 = *reinterpret_cast<const float4*>(&As[dd][4*ty]);
                const float4 a1 = *reinterpret_cast<const float4*>(&As[dd][4*ty + 64]);
                const float4 b0 = *reinterpret_cast<const float4*>(&Bs[dd][4*tx]);
                const float4 b1 = *reinterpret_cast<const float4*>(&Bs[dd][4*tx + 64]);
                const float aa[8] = {a0.x,a0.y,a0.z,a0.w,a1.x,a1.y,a1.z,a1.w};
                const float bb[8] = {b0.x,b0.y,b0.z,b0.w,b1.x,b1.y,b1.z,b1.w};
                #pragma unroll
                for (int r = 0; r < 8; ++r)
                    #pragma unroll
                    for (int j = 0; j < 8; ++j)
                        acc[r][j] = fmaf(aa[r], bb[j], acc[r][j]);
            }
            __syncthreads();
        }
        #pragma unroll
        for (int r = 0; r < 8; ++r) {
            float mv = 3.4e38f; int mi = 0x7fffffff;
            #pragma unroll
            for (int j = 0; j < 8; ++j) {
                int c = k0 + ((j < 4) ? (4*tx + j) : (64 + 4*tx + (j-4)));
                float t1   = __fadd_rn(slr[r], CN[c]);      // fl(SL + CN)
                float u    = __fmul_rn(2.0f, acc[r][j]);    // exact
                float dist = __fadd_rn(t1, -u);             // fl(t1 - 2P)
                if (dist < mv || (dist == mv && c < mi)) { mv = dist; mi = c; }
            }
            #pragma unroll
            for (int m = 1; m < 16; m <<= 1) {
                float ov = __shfl_xor(mv, m, 16);
                int   oi = __shfl_xor(mi, m, 16);
                if (ov < mv || (ov == mv && oi < mi)) { mv = ov; mi = oi; }
            }
            if (mv < bestv[r] || (mv == bestv[r] && mi < besti[r])) {
                bestv[r] = mv; besti[r] = mi;
            }
        }
    }
    if (tx == 0) {
        #pragma unroll
        for (int gr = 0; gr < 2; ++gr)
            #pragma unroll
            for (int r = 0; r < 4; ++r) {
                int row = 64*gr + 4*ty + r;
                outInd[bm + row] = (float)besti[gr*4+r];
                sIdx[row] = besti[gr*4+r];
            }
    }
    __syncthreads();
    float lsum = 0.f;
    #pragma unroll
    for (int p = 0; p < 16; ++p) {
        int q   = tid + p*256;
        int row = q >> 5;
        int d4  = (q & 31) * 4;
        int ci  = sIdx[row];
        const float4 qv = *reinterpret_cast<const float4*>(&CB[(size_t)ci*DIM + d4]);
        const float4 lv = *reinterpret_cast<const float4*>(&L[(size_t)(bm+row)*DIM + d4]);
        *reinterpret_cast<float4*>(&outQ[(size_t)(bm+row)*DIM + d4]) = qv;
        float dx = qv.x - lv.x, dy = qv.y - lv.y, dz = qv.z - lv.z, dw = qv.w - lv.w;
        lsum += dx*dx + dy*dy + dz*dz + dw*dw;
    }
    #pragma unroll
    for (int s = 32; s; s >>= 1) lsum += __shfl_down(lsum, s, 64);
    __shared__ float part[4];
    if ((tid & 63) == 0) part[tid >> 6] = lsum;
    __syncthreads();
    if (tid == 0) atomicAdd(lossAcc, part[0] + part[1] + part[2] + part[3]);
}

// ---------------------------------------------------------------------------
// Decoder layer 3: tanh head — wave per row (validated)
// ---------------------------------------------------------------------------
__global__ __launch_bounds__(256) void dec3_kernel(const float* __restrict__ d2,
                                                   const float* __restrict__ Wd3,
                                                   const float* __restrict__ bd3,
                                                   float* __restrict__ out)
{
    const int w = threadIdx.x >> 6, lane = threadIdx.x & 63;
    const int n = blockIdx.x * 4 + w;
    float acc[6] = {0.f, 0.f, 0.f, 0.f, 0.f, 0.f};
    for (int k = lane; k < HID; k += 64) {
        float v = d2[(size_t)n*HID + k];
        #pragma unroll
        for (int o = 0; o < 6; ++o) acc[o] = fmaf(v, Wd3[k*6 + o], acc[o]);
    }
    #pragma unroll
    for (int o = 0; o < 6; ++o)
        #pragma unroll
        for (int s = 32; s; s >>= 1) acc[o] += __shfl_down(acc[o], s, 64);
    if (lane == 0) {
        #pragma unroll
        for (int o = 0; o < 6; ++o)
            out[(size_t)n*6 + o] = tanhf(__fadd_rn(acc[o], bd3[o]));
    }
}

__global__ void zero1_kernel(float* __restrict__ p) { p[0] = 0.f; }

__global__ void loss_final_kernel(const float* __restrict__ lossAcc,
                                  float* __restrict__ out)
{
    out[0] = 1.25f * lossAcc[0] / (float)(NROWS * DIM);
}

// ---------------------------------------------------------------------------
extern "C" void kernel_launch(void* const* d_in, const int* in_sizes, int n_in,
                              void* d_out, int out_size, void* d_ws, size_t ws_size,
                              hipStream_t stream)
{
    const float* action = (const float*)d_in[0];
    const float* W1  = (const float*)d_in[1];
    const float* b1  = (const float*)d_in[2];
    const float* W2  = (const float*)d_in[3];
    const float* b2  = (const float*)d_in[4];
    const float* Wmu = (const float*)d_in[5];
    const float* bmu = (const float*)d_in[6];
    const float* CB  = (const float*)d_in[7];
    const float* Wd1 = (const float*)d_in[8];
    const float* bd1 = (const float*)d_in[9];
    const float* Wd2 = (const float*)d_in[10];
    const float* bd2 = (const float*)d_in[11];
    const float* Wd3 = (const float*)d_in[12];
    const float* bd3 = (const float*)d_in[13];

    float* out = (float*)d_out;
    const size_t o1 = NROWS;
    const size_t o2 = o1 + (size_t)NROWS*DIM;
    const size_t o3 = o2 + (size_t)NROWS*6;

    int ch = 8192;
    size_t need = 0;
    while (true) {
        need = 2*(size_t)ch*HID*4 + (size_t)NROWS*DIM*4 + (size_t)NROWS*4
             + (size_t)KCODE*4 + 64
             + (size_t)ch*3*HID*2 + (size_t)HID*3*DIM*2 + (size_t)HID*3*HID*2;
        if (need <= ws_size || ch <= 128) break;
        ch >>= 1;
    }
    if (need > ws_size) return;

    char* ws = (char*)d_ws;
    size_t off = 0;
    float* bufA    = (float*)(ws + off); off += (size_t)ch*HID*4;
    float* bufB    = (float*)(ws + off); off += (size_t)ch*HID*4;
    float* latF    = (float*)(ws + off); off += (size_t)NROWS*DIM*4;
    float* slF     = (float*)(ws + off); off += (size_t)NROWS*4;
    float* cnorm   = (float*)(ws + off); off += (size_t)KCODE*4;
    float* lossAcc = (float*)(ws + off); off += 64;
    unsigned short* Abf = (unsigned short*)(ws + off); off += (size_t)ch*3*HID*2;
    unsigned short* W1T = (unsigned short*)(ws + off); off += (size_t)HID*3*DIM*2;
    unsigned short* W2T = (unsigned short*)(ws + off);

    zero1_kernel<<<1, 1, 0, stream>>>(lossAcc);
    rownorm_np_kernel<<<dim3(KCODE/128), 128, 0, stream>>>(CB, KCODE, cnorm);
    convW_kernel<<<dim3(512), 256, 0, stream>>>(Wd1, W1T, DIM, HID);
    convW_kernel<<<dim3(1024), 256, 0, stream>>>(Wd2, W2T, HID, HID);

    // ---- encoder (chunked, bit-exact fp32) -> full latents
    for (int c0 = 0; c0 < NROWS; c0 += ch) {
        enc1_kernel<<<dim3(HID/256, ch), 256, 0, stream>>>(action + (size_t)c0*6, W1, b1, bufA);
        gemm8_kernel<1><<<dim3(HID/128, ch/128), 256, 0, stream>>>(bufA, W2, b2, bufB, ch, HID, HID);
        gemm8_kernel<0><<<dim3(1, ch/128), 256, 0, stream>>>(bufB, Wmu, bmu, latF + (size_t)c0*DIM, ch, HID, DIM);
    }

    // ---- VQ (bit-exact fp32, full N, 256 blocks x 128 rows)
    rownorm_np_kernel<<<dim3(NROWS/128), 128, 0, stream>>>(latF, NROWS, slF);
    vq_kernel<<<dim3(NROWS/128), 256, 0, stream>>>(latF, CB, slF, cnorm, out, out + o1, lossAcc);

    // ---- decoder (chunked, split-bf16 MFMA)
    for (int c0 = 0; c0 < NROWS; c0 += ch) {
        const float* qC = out + o1 + (size_t)c0*DIM;
        convA_kernel<<<dim3(1024), 256, 0, stream>>>(qC, Abf, ch, DIM);
        gemm_bf16_kernel<1><<<dim3(HID/128, ch/128), 256, 0, stream>>>(Abf, W1T, bd1, bufA, ch, 3*DIM, HID);
        convA_kernel<<<dim3(2048), 256, 0, stream>>>(bufA, Abf, ch, HID);
        gemm_bf16_kernel<1><<<dim3(HID/128, ch/128), 256, 0, stream>>>(Abf, W2T, bd2, bufB, ch, 3*HID, HID);
        dec3_kernel<<<dim3(ch/4), 256, 0, stream>>>(bufB, Wd3, bd3, out + o2 + (size_t)c0*6);
    }

    loss_final_kernel<<<1, 1, 0, stream>>>(lossAcc, out + o3);
}

// Round 10
// 2146.070 us; speedup vs baseline: 1.3206x; 1.3206x over previous
//
#include <hip/hip_runtime.h>
#include <cmath>

#define NROWS 32768
#define HID   1024
#define DIM   128
#define KCODE 4096
#define QBLK  384   // OpenBLAS sgemm kc (validated round 4): folds at 384,768,1024

typedef __attribute__((ext_vector_type(8))) short short8;
typedef __attribute__((ext_vector_type(4))) float f32x4;

// ---------------------------------------------------------------------------
// Encoder layer 1 (bit-exact, validated)
// ---------------------------------------------------------------------------
__global__ __launch_bounds__(256) void enc1_kernel(const float* __restrict__ act,
                                                   const float* __restrict__ W1,
                                                   const float* __restrict__ b1,
                                                   float* __restrict__ h1)
{
    const int h = blockIdx.x * 256 + threadIdx.x;
    const int n = blockIdx.y;
    float a0 = act[n*6+0], a1 = act[n*6+1], a2 = act[n*6+2];
    float a3 = act[n*6+3], a4 = act[n*6+4], a5 = act[n*6+5];
    float acc = 0.f;
    acc = fmaf(a0, W1[0*HID + h], acc);
    acc = fmaf(a1, W1[1*HID + h], acc);
    acc = fmaf(a2, W1[2*HID + h], acc);
    acc = fmaf(a3, W1[3*HID + h], acc);
    acc = fmaf(a4, W1[4*HID + h], acc);
    acc = fmaf(a5, W1[5*HID + h], acc);
    acc = __fadd_rn(acc, b1[h]);
    h1[(size_t)n*HID + h] = fmaxf(acc, 0.f);
}

// ---------------------------------------------------------------------------
// fp32 GEMM, bit-exact k-chain (validated rounds 7/8) — ENCODER ONLY
// ---------------------------------------------------------------------------
template<int BM, int ACT>
__global__ __launch_bounds__(256, 2) void gemm_kernel(const float* __restrict__ A,
                                                      const float* __restrict__ B,
                                                      const float* __restrict__ bias,
                                                      float* __restrict__ C,
                                                      int M, int K, int Nn)
{
    const int tid = threadIdx.x;
    const int tx = tid & 15, ty = tid >> 4;
    constexpr int G = BM / 64;
    const int bn = blockIdx.x * 128;
    const int bm = blockIdx.y * BM;

    __shared__ float As[32][BM + 4];
    __shared__ float Bs[32][132];

    float accB[4*G][8];
    float accC[4*G][8];
    #pragma unroll
    for (int i = 0; i < 4*G; ++i)
        #pragma unroll
        for (int j = 0; j < 8; ++j) { accB[i][j] = 0.f; accC[i][j] = 0.f; }

    for (int kt = 0; kt < K; kt += 32) {
        #pragma unroll
        for (int p = 0; p < BM/32; ++p) {
            int idx = tid + p*256;
            int row = idx >> 3;
            int k4  = (idx & 7) * 4;
            const float4 v = *reinterpret_cast<const float4*>(&A[(size_t)(bm+row)*K + kt + k4]);
            As[k4+0][row] = v.x; As[k4+1][row] = v.y;
            As[k4+2][row] = v.z; As[k4+3][row] = v.w;
        }
        #pragma unroll
        for (int p = 0; p < 4; ++p) {
            int idx  = tid + p*256;
            int krow = idx >> 5;
            int n4   = (idx & 31) * 4;
            *reinterpret_cast<float4*>(&Bs[krow][n4]) =
                *reinterpret_cast<const float4*>(&B[(size_t)(kt+krow)*Nn + bn + n4]);
        }
        __syncthreads();
        #pragma unroll
        for (int kk = 0; kk < 32; ++kk) {
            const float4 b0 = *reinterpret_cast<const float4*>(&Bs[kk][4*tx]);
            const float4 b1 = *reinterpret_cast<const float4*>(&Bs[kk][4*tx + 64]);
            const float bb[8] = {b0.x,b0.y,b0.z,b0.w,b1.x,b1.y,b1.z,b1.w};
            #pragma unroll
            for (int g = 0; g < G; ++g) {
                const float4 a = *reinterpret_cast<const float4*>(&As[kk][4*ty + 64*g]);
                const float aa[4] = {a.x,a.y,a.z,a.w};
                #pragma unroll
                for (int r = 0; r < 4; ++r)
                    #pragma unroll
                    for (int j = 0; j < 8; ++j)
                        accB[g*4+r][j] = fmaf(aa[r], bb[j], accB[g*4+r][j]);
            }
        }
        __syncthreads();
        if ((((kt + 32) % QBLK) == 0) || (kt + 32 >= K)) {
            #pragma unroll
            for (int i = 0; i < 4*G; ++i)
                #pragma unroll
                for (int j = 0; j < 8; ++j) {
                    accC[i][j] = __fadd_rn(accC[i][j], accB[i][j]);
                    accB[i][j] = 0.f;
                }
        }
    }
    const float4 bv0 = *reinterpret_cast<const float4*>(&bias[bn + 4*tx]);
    const float4 bv1 = *reinterpret_cast<const float4*>(&bias[bn + 4*tx + 64]);
    const float bb[8] = {bv0.x,bv0.y,bv0.z,bv0.w,bv1.x,bv1.y,bv1.z,bv1.w};
    #pragma unroll
    for (int g = 0; g < G; ++g)
        #pragma unroll
        for (int r = 0; r < 4; ++r) {
            const int i = g*4 + r;
            const int row = bm + 64*g + 4*ty + r;
            float o[8];
            #pragma unroll
            for (int j = 0; j < 8; ++j) {
                float v = __fadd_rn(accC[i][j], bb[j]);
                if (ACT == 1) v = fmaxf(v, 0.f);
                o[j] = v;
            }
            *reinterpret_cast<float4*>(&C[(size_t)row*Nn + bn + 4*tx])      = make_float4(o[0],o[1],o[2],o[3]);
            *reinterpret_cast<float4*>(&C[(size_t)row*Nn + bn + 64 + 4*tx]) = make_float4(o[4],o[5],o[6],o[7]);
        }
}

// ---------------------------------------------------------------------------
// bf16 helpers (RNE)
// ---------------------------------------------------------------------------
__device__ inline unsigned short bf16_rne(float x) {
    union { float f; unsigned u; } a; a.f = x;
    unsigned r = a.u + 0x7FFFu + ((a.u >> 16) & 1u);
    return (unsigned short)(r >> 16);
}

// W [K][N] fp32 -> WT [N][K] bf16 (plain cast, transposed for B-side rows)
__global__ __launch_bounds__(256) void convW_kernel(const float* __restrict__ W,
                                                    unsigned short* __restrict__ WT,
                                                    int K, int N)
{
    const int total = K * N;
    for (int t = blockIdx.x*256 + threadIdx.x; t < total; t += gridDim.x*256) {
        int k = t / N, n = t - k*N;
        WT[(size_t)n*K + k] = bf16_rne(W[(size_t)k*N + n]);
    }
}

// ---------------------------------------------------------------------------
// bf16 MFMA GEMM with FUSED fp32->bf16 A-cast in LDS staging.
// C = act(bf16(A[M][K]) @ BT[N][K]^T + bias), 128x128 tile, 4 waves (2x2),
// 4x4 16x16x32 fragments/wave, XOR-swizzled LDS.
// ---------------------------------------------------------------------------
template<int ACT>
__global__ __launch_bounds__(256) void gemm_bf16_kernel(const float* __restrict__ A,
                                                        const unsigned short* __restrict__ BT,
                                                        const float* __restrict__ bias,
                                                        float* __restrict__ C,
                                                        int M, int K, int Nn)
{
    __shared__ unsigned short Asm[128*64];
    __shared__ unsigned short Bsm[128*64];
    const int tid  = threadIdx.x;
    const int lane = tid & 63;
    const int wave = tid >> 6;
    const int wr = wave >> 1, wc = wave & 1;
    const int bm = blockIdx.y * 128, bn = blockIdx.x * 128;
    const int l15 = lane & 15, l4 = lane >> 4;

    f32x4 acc[4][4];
    #pragma unroll
    for (int i = 0; i < 4; ++i)
        #pragma unroll
        for (int j = 0; j < 4; ++j) acc[i][j] = (f32x4){0.f,0.f,0.f,0.f};

    const int srow = tid >> 3;
    const int sch  = (tid & 7) * 8;        // bf16 elements within 64-wide k-tile
    for (int kt = 0; kt < K; kt += 64) {
        #pragma unroll
        for (int p = 0; p < 4; ++p) {
            int row = srow + 32*p;
            // A: load 8 fp32, cast RNE to 8 bf16
            const float4 f0 = *reinterpret_cast<const float4*>(&A[(size_t)(bm+row)*K + kt + sch]);
            const float4 f1 = *reinterpret_cast<const float4*>(&A[(size_t)(bm+row)*K + kt + sch + 4]);
            short8 va;
            va[0] = (short)bf16_rne(f0.x); va[1] = (short)bf16_rne(f0.y);
            va[2] = (short)bf16_rne(f0.z); va[3] = (short)bf16_rne(f0.w);
            va[4] = (short)bf16_rne(f1.x); va[5] = (short)bf16_rne(f1.y);
            va[6] = (short)bf16_rne(f1.z); va[7] = (short)bf16_rne(f1.w);
            // B: already bf16
            short8 vb = *reinterpret_cast<const short8*>(&BT[(size_t)(bn+row)*K + kt + sch]);
            int byte = (row*128 + sch*2) ^ ((row & 7) << 4);
            *reinterpret_cast<short8*>((char*)Asm + byte) = va;
            *reinterpret_cast<short8*>((char*)Bsm + byte) = vb;
        }
        __syncthreads();
        #pragma unroll
        for (int ks = 0; ks < 64; ks += 32) {
            const int kk2 = (ks + l4*8) * 2;
            short8 af[4], bf[4];
            #pragma unroll
            for (int i = 0; i < 4; ++i) {
                int mrow = wr*64 + i*16 + l15;
                af[i] = *reinterpret_cast<const short8*>((char*)Asm + ((mrow*128 + kk2) ^ ((mrow & 7) << 4)));
                int nrow = wc*64 + i*16 + l15;
                bf[i] = *reinterpret_cast<const short8*>((char*)Bsm + ((nrow*128 + kk2) ^ ((nrow & 7) << 4)));
            }
            #pragma unroll
            for (int i = 0; i < 4; ++i)
                #pragma unroll
                for (int j = 0; j < 4; ++j)
                    acc[i][j] = __builtin_amdgcn_mfma_f32_16x16x32_bf16(af[i], bf[j], acc[i][j], 0, 0, 0);
        }
        __syncthreads();
    }
    #pragma unroll
    for (int j = 0; j < 4; ++j) {
        const int col = bn + wc*64 + j*16 + l15;
        const float bv = bias[col];
        #pragma unroll
        for (int i = 0; i < 4; ++i) {
            #pragma unroll
            for (int r = 0; r < 4; ++r) {
                const int row = bm + wr*64 + i*16 + l4*4 + r;
                float v = acc[i][j][r] + bv;
                if (ACT == 1) v = fmaxf(v, 0.f);
                C[(size_t)row*Nn + col] = v;
            }
        }
    }
}

// ---------------------------------------------------------------------------
// numpy pairwise row-norm (validated bit-exact)
// ---------------------------------------------------------------------------
__global__ __launch_bounds__(128) void rownorm_np_kernel(const float* __restrict__ X,
                                                         int nrows,
                                                         float* __restrict__ out)
{
    const int r = blockIdx.x * 128 + threadIdx.x;
    if (r >= nrows) return;
    const float* p = X + (size_t)r * DIM;
    float lane[16];
    #pragma unroll
    for (int l = 0; l < 16; ++l) {
        float x0 = p[0*16 + l],  y0 = p[64 + 0*16 + l];
        float x1 = p[1*16 + l],  y1 = p[64 + 1*16 + l];
        float a0 = __fadd_rn(__fmul_rn(x0, x0), __fmul_rn(y0, y0));
        float a1 = __fadd_rn(__fmul_rn(x1, x1), __fmul_rn(y1, y1));
        float r01 = __fadd_rn(a0, a1);
        float x2 = p[2*16 + l],  y2 = p[64 + 2*16 + l];
        float x3 = p[3*16 + l],  y3 = p[64 + 3*16 + l];
        float a2 = __fadd_rn(__fmul_rn(x2, x2), __fmul_rn(y2, y2));
        float a3 = __fadd_rn(__fmul_rn(x3, x3), __fmul_rn(y3, y3));
        float r23 = __fadd_rn(a2, a3);
        lane[l] = __fadd_rn(r01, r23);
    }
    float s[8];
    #pragma unroll
    for (int l = 0; l < 8; ++l) s[l] = __fadd_rn(lane[l], lane[l+8]);
    float u[4];
    #pragma unroll
    for (int l = 0; l < 4; ++l) u[l] = __fadd_rn(s[l], s[l+4]);
    float v0 = __fadd_rn(u[0], u[2]);
    float v1 = __fadd_rn(u[1], u[3]);
    out[r] = __fadd_rn(v0, v1);
}

// ---------------------------------------------------------------------------
// Fused VQ (validated round 7/8 config — 64 rows/block, 512 blocks)
// ---------------------------------------------------------------------------
__global__ __launch_bounds__(256, 2) void vq_kernel(const float* __restrict__ L,
                                                    const float* __restrict__ CB,
                                                    const float* __restrict__ SL,
                                                    const float* __restrict__ CN,
                                                    float* __restrict__ outInd,
                                                    float* __restrict__ outQ,
                                                    float* __restrict__ lossAcc)
{
    const int tid = threadIdx.x;
    const int tx = tid & 15, ty = tid >> 4;
    const int bm = blockIdx.x * 64;

    __shared__ float As[32][68];
    __shared__ float Bs[32][132];
    __shared__ int   sIdx[64];

    float slr[4], bestv[4];
    int   besti[4];
    #pragma unroll
    for (int r = 0; r < 4; ++r) {
        slr[r] = SL[bm + 4*ty + r];
        bestv[r] = 3.4e38f; besti[r] = 0x7fffffff;
    }

    for (int k0 = 0; k0 < KCODE; k0 += 128) {
        float acc[4][8];
        #pragma unroll
        for (int r = 0; r < 4; ++r)
            #pragma unroll
            for (int j = 0; j < 8; ++j) acc[r][j] = 0.f;

        for (int d0 = 0; d0 < DIM; d0 += 32) {
            #pragma unroll
            for (int p = 0; p < 2; ++p) {
                int idx = tid + p*256;
                int row = idx >> 3;
                int d4  = (idx & 7) * 4;
                const float4 v = *reinterpret_cast<const float4*>(&L[(size_t)(bm+row)*DIM + d0 + d4]);
                As[d4+0][row] = v.x; As[d4+1][row] = v.y;
                As[d4+2][row] = v.z; As[d4+3][row] = v.w;
            }
            #pragma unroll
            for (int p = 0; p < 4; ++p) {
                int idx  = tid + p*256;
                int crow = idx >> 3;
                int d4   = (idx & 7) * 4;
                const float4 w = *reinterpret_cast<const float4*>(&CB[(size_t)(k0+crow)*DIM + d0 + d4]);
                Bs[d4+0][crow] = w.x; Bs[d4+1][crow] = w.y;
                Bs[d4+2][crow] = w.z; Bs[d4+3][crow] = w.w;
            }
            __syncthreads();
            #pragma unroll
            for (int dd = 0; dd < 32; ++dd) {
                const float4 a  = *reinterpret_cast<const float4*>(&As[dd][4*ty]);
                const float4 b0 = *reinterpret_cast<const float4*>(&Bs[dd][4*tx]);
                const float4 b1 = *reinterpret_cast<const float4*>(&Bs[dd][4*tx + 64]);
                const float aa[4] = {a.x,a.y,a.z,a.w};
                const float bb[8] = {b0.x,b0.y,b0.z,b0.w,b1.x,b1.y,b1.z,b1.w};
                #pragma unroll
                for (int r = 0; r < 4; ++r)
                    #pragma unroll
                    for (int j = 0; j < 8; ++j)
                        acc[r][j] = fmaf(aa[r], bb[j], acc[r][j]);
            }
            __syncthreads();
        }
        #pragma unroll
        for (int r = 0; r < 4; ++r) {
            float mv = 3.4e38f; int mi = 0x7fffffff;
            #pragma unroll
            for (int j = 0; j < 8; ++j) {
                int c = k0 + ((j < 4) ? (4*tx + j) : (64 + 4*tx + (j-4)));
                float t1   = __fadd_rn(slr[r], CN[c]);
                float u    = __fmul_rn(2.0f, acc[r][j]);
                float dist = __fadd_rn(t1, -u);
                if (dist < mv || (dist == mv && c < mi)) { mv = dist; mi = c; }
            }
            #pragma unroll
            for (int m = 1; m < 16; m <<= 1) {
                float ov = __shfl_xor(mv, m, 16);
                int   oi = __shfl_xor(mi, m, 16);
                if (ov < mv || (ov == mv && oi < mi)) { mv = ov; mi = oi; }
            }
            if (mv < bestv[r] || (mv == bestv[r] && mi < besti[r])) {
                bestv[r] = mv; besti[r] = mi;
            }
        }
    }
    if (tx == 0) {
        #pragma unroll
        for (int r = 0; r < 4; ++r) {
            int row = 4*ty + r;
            outInd[bm + row] = (float)besti[r];
            sIdx[row] = besti[r];
        }
    }
    __syncthreads();
    float lsum = 0.f;
    #pragma unroll
    for (int p = 0; p < 8; ++p) {
        int q   = tid + p*256;
        int row = q >> 5;
        int d4  = (q & 31) * 4;
        int ci  = sIdx[row];
        const float4 qv = *reinterpret_cast<const float4*>(&CB[(size_t)ci*DIM + d4]);
        const float4 lv = *reinterpret_cast<const float4*>(&L[(size_t)(bm+row)*DIM + d4]);
        *reinterpret_cast<float4*>(&outQ[(size_t)(bm+row)*DIM + d4]) = qv;
        float dx = qv.x - lv.x, dy = qv.y - lv.y, dz = qv.z - lv.z, dw = qv.w - lv.w;
        lsum += dx*dx + dy*dy + dz*dz + dw*dw;
    }
    #pragma unroll
    for (int s = 32; s; s >>= 1) lsum += __shfl_down(lsum, s, 64);
    __shared__ float part[4];
    if ((tid & 63) == 0) part[tid >> 6] = lsum;
    __syncthreads();
    if (tid == 0) atomicAdd(lossAcc, part[0] + part[1] + part[2] + part[3]);
}

// ---------------------------------------------------------------------------
// Decoder layer 3: tanh head — wave per row (validated)
// ---------------------------------------------------------------------------
__global__ __launch_bounds__(256) void dec3_kernel(const float* __restrict__ d2,
                                                   const float* __restrict__ Wd3,
                                                   const float* __restrict__ bd3,
                                                   float* __restrict__ out)
{
    const int w = threadIdx.x >> 6, lane = threadIdx.x & 63;
    const int n = blockIdx.x * 4 + w;
    float acc[6] = {0.f, 0.f, 0.f, 0.f, 0.f, 0.f};
    for (int k = lane; k < HID; k += 64) {
        float v = d2[(size_t)n*HID + k];
        #pragma unroll
        for (int o = 0; o < 6; ++o) acc[o] = fmaf(v, Wd3[k*6 + o], acc[o]);
    }
    #pragma unroll
    for (int o = 0; o < 6; ++o)
        #pragma unroll
        for (int s = 32; s; s >>= 1) acc[o] += __shfl_down(acc[o], s, 64);
    if (lane == 0) {
        #pragma unroll
        for (int o = 0; o < 6; ++o)
            out[(size_t)n*6 + o] = tanhf(__fadd_rn(acc[o], bd3[o]));
    }
}

__global__ void zero1_kernel(float* __restrict__ p) { p[0] = 0.f; }

__global__ void loss_final_kernel(const float* __restrict__ lossAcc,
                                  float* __restrict__ out)
{
    out[0] = 1.25f * lossAcc[0] / (float)(NROWS * DIM);
}

// ---------------------------------------------------------------------------
extern "C" void kernel_launch(void* const* d_in, const int* in_sizes, int n_in,
                              void* d_out, int out_size, void* d_ws, size_t ws_size,
                              hipStream_t stream)
{
    const float* action = (const float*)d_in[0];
    const float* W1  = (const float*)d_in[1];
    const float* b1  = (const float*)d_in[2];
    const float* W2  = (const float*)d_in[3];
    const float* b2  = (const float*)d_in[4];
    const float* Wmu = (const float*)d_in[5];
    const float* bmu = (const float*)d_in[6];
    const float* CB  = (const float*)d_in[7];
    const float* Wd1 = (const float*)d_in[8];
    const float* bd1 = (const float*)d_in[9];
    const float* Wd2 = (const float*)d_in[10];
    const float* bd2 = (const float*)d_in[11];
    const float* Wd3 = (const float*)d_in[12];
    const float* bd3 = (const float*)d_in[13];

    float* out = (float*)d_out;
    const size_t o1 = NROWS;
    const size_t o2 = o1 + (size_t)NROWS*DIM;
    const size_t o3 = o2 + (size_t)NROWS*6;

    int ch = 8192;
    size_t need = 0;
    while (true) {
        need = 2*(size_t)ch*HID*4 + (size_t)NROWS*DIM*4 + (size_t)NROWS*4
             + (size_t)KCODE*4 + 64
             + (size_t)HID*DIM*2 + (size_t)HID*HID*2;
        if (need <= ws_size || ch <= 128) break;
        ch >>= 1;
    }
    if (need > ws_size) return;

    char* ws = (char*)d_ws;
    size_t off = 0;
    float* bufA    = (float*)(ws + off); off += (size_t)ch*HID*4;
    float* bufB    = (float*)(ws + off); off += (size_t)ch*HID*4;
    float* latF    = (float*)(ws + off); off += (size_t)NROWS*DIM*4;
    float* slF     = (float*)(ws + off); off += (size_t)NROWS*4;
    float* cnorm   = (float*)(ws + off); off += (size_t)KCODE*4;
    float* lossAcc = (float*)(ws + off); off += 64;
    unsigned short* W1T = (unsigned short*)(ws + off); off += (size_t)HID*DIM*2;
    unsigned short* W2T = (unsigned short*)(ws + off);

    zero1_kernel<<<1, 1, 0, stream>>>(lossAcc);
    rownorm_np_kernel<<<dim3(KCODE/128), 128, 0, stream>>>(CB, KCODE, cnorm);
    convW_kernel<<<dim3(256), 256, 0, stream>>>(Wd1, W1T, DIM, HID);
    convW_kernel<<<dim3(1024), 256, 0, stream>>>(Wd2, W2T, HID, HID);

    // ---- encoder (chunked, bit-exact fp32) -> full latents
    for (int c0 = 0; c0 < NROWS; c0 += ch) {
        enc1_kernel<<<dim3(HID/256, ch), 256, 0, stream>>>(action + (size_t)c0*6, W1, b1, bufA);
        gemm_kernel<128,1><<<dim3(HID/128, ch/128), 256, 0, stream>>>(bufA, W2, b2, bufB, ch, HID, HID);
        gemm_kernel<64,0><<<dim3(1, ch/64), 256, 0, stream>>>(bufB, Wmu, bmu, latF + (size_t)c0*DIM, ch, HID, DIM);
    }

    // ---- VQ (bit-exact fp32, full N, 512 blocks)
    rownorm_np_kernel<<<dim3(NROWS/128), 128, 0, stream>>>(latF, NROWS, slF);
    vq_kernel<<<dim3(NROWS/64), 256, 0, stream>>>(latF, CB, slF, cnorm, out, out + o1, lossAcc);

    // ---- decoder (chunked, plain-bf16 MFMA with fused A-cast)
    for (int c0 = 0; c0 < NROWS; c0 += ch) {
        const float* qC = out + o1 + (size_t)c0*DIM;
        gemm_bf16_kernel<1><<<dim3(HID/128, ch/128), 256, 0, stream>>>(qC, W1T, bd1, bufA, ch, DIM, HID);
        gemm_bf16_kernel<1><<<dim3(HID/128, ch/128), 256, 0, stream>>>(bufA, W2T, bd2, bufB, ch, HID, HID);
        dec3_kernel<<<dim3(ch/4), 256, 0, stream>>>(bufB, Wd3, bd3, out + o2 + (size_t)c0*6);
    }

    loss_final_kernel<<<1, 1, 0, stream>>>(lossAcc, out + o3);
}

// Round 14
// 2114.818 us; speedup vs baseline: 1.3401x; 1.0148x over previous
//
#include <hip/hip_runtime.h>
#include <cmath>

#define NROWS 32768
#define HID   1024
#define DIM   128
#define KCODE 4096
#define QBLK  384   // OpenBLAS sgemm kc (validated round 4): folds at 384,768,1024

typedef __attribute__((ext_vector_type(8))) short short8;
typedef __attribute__((ext_vector_type(4))) float f32x4;

// ---------------------------------------------------------------------------
// Encoder layer 1 (bit-exact, validated)
// ---------------------------------------------------------------------------
__global__ __launch_bounds__(256) void enc1_kernel(const float* __restrict__ act,
                                                   const float* __restrict__ W1,
                                                   const float* __restrict__ b1,
                                                   float* __restrict__ h1)
{
    const int h = blockIdx.x * 256 + threadIdx.x;
    const int n = blockIdx.y;
    float a0 = act[n*6+0], a1 = act[n*6+1], a2 = act[n*6+2];
    float a3 = act[n*6+3], a4 = act[n*6+4], a5 = act[n*6+5];
    float acc = 0.f;
    acc = fmaf(a0, W1[0*HID + h], acc);
    acc = fmaf(a1, W1[1*HID + h], acc);
    acc = fmaf(a2, W1[2*HID + h], acc);
    acc = fmaf(a3, W1[3*HID + h], acc);
    acc = fmaf(a4, W1[4*HID + h], acc);
    acc = fmaf(a5, W1[5*HID + h], acc);
    acc = __fadd_rn(acc, b1[h]);
    h1[(size_t)n*HID + h] = fmaxf(acc, 0.f);
}

// ---------------------------------------------------------------------------
// fp32 GEMM, bit-exact k-chain (validated rounds 7/8/10) — ENCODER ONLY
// ---------------------------------------------------------------------------
template<int BM, int ACT>
__global__ __launch_bounds__(256, 2) void gemm_kernel(const float* __restrict__ A,
                                                      const float* __restrict__ B,
                                                      const float* __restrict__ bias,
                                                      float* __restrict__ C,
                                                      int M, int K, int Nn)
{
    const int tid = threadIdx.x;
    const int tx = tid & 15, ty = tid >> 4;
    constexpr int G = BM / 64;
    const int bn = blockIdx.x * 128;
    const int bm = blockIdx.y * BM;

    __shared__ float As[32][BM + 4];
    __shared__ float Bs[32][132];

    float accB[4*G][8];
    float accC[4*G][8];
    #pragma unroll
    for (int i = 0; i < 4*G; ++i)
        #pragma unroll
        for (int j = 0; j < 8; ++j) { accB[i][j] = 0.f; accC[i][j] = 0.f; }

    for (int kt = 0; kt < K; kt += 32) {
        #pragma unroll
        for (int p = 0; p < BM/32; ++p) {
            int idx = tid + p*256;
            int row = idx >> 3;
            int k4  = (idx & 7) * 4;
            const float4 v = *reinterpret_cast<const float4*>(&A[(size_t)(bm+row)*K + kt + k4]);
            As[k4+0][row] = v.x; As[k4+1][row] = v.y;
            As[k4+2][row] = v.z; As[k4+3][row] = v.w;
        }
        #pragma unroll
        for (int p = 0; p < 4; ++p) {
            int idx  = tid + p*256;
            int krow = idx >> 5;
            int n4   = (idx & 31) * 4;
            *reinterpret_cast<float4*>(&Bs[krow][n4]) =
                *reinterpret_cast<const float4*>(&B[(size_t)(kt+krow)*Nn + bn + n4]);
        }
        __syncthreads();
        #pragma unroll
        for (int kk = 0; kk < 32; ++kk) {
            const float4 b0 = *reinterpret_cast<const float4*>(&Bs[kk][4*tx]);
            const float4 b1 = *reinterpret_cast<const float4*>(&Bs[kk][4*tx + 64]);
            const float bb[8] = {b0.x,b0.y,b0.z,b0.w,b1.x,b1.y,b1.z,b1.w};
            #pragma unroll
            for (int g = 0; g < G; ++g) {
                const float4 a = *reinterpret_cast<const float4*>(&As[kk][4*ty + 64*g]);
                const float aa[4] = {a.x,a.y,a.z,a.w};
                #pragma unroll
                for (int r = 0; r < 4; ++r)
                    #pragma unroll
                    for (int j = 0; j < 8; ++j)
                        accB[g*4+r][j] = fmaf(aa[r], bb[j], accB[g*4+r][j]);
            }
        }
        __syncthreads();
        if ((((kt + 32) % QBLK) == 0) || (kt + 32 >= K)) {
            #pragma unroll
            for (int i = 0; i < 4*G; ++i)
                #pragma unroll
                for (int j = 0; j < 8; ++j) {
                    accC[i][j] = __fadd_rn(accC[i][j], accB[i][j]);
                    accB[i][j] = 0.f;
                }
        }
    }
    const float4 bv0 = *reinterpret_cast<const float4*>(&bias[bn + 4*tx]);
    const float4 bv1 = *reinterpret_cast<const float4*>(&bias[bn + 4*tx + 64]);
    const float bb[8] = {bv0.x,bv0.y,bv0.z,bv0.w,bv1.x,bv1.y,bv1.z,bv1.w};
    #pragma unroll
    for (int g = 0; g < G; ++g)
        #pragma unroll
        for (int r = 0; r < 4; ++r) {
            const int i = g*4 + r;
            const int row = bm + 64*g + 4*ty + r;
            float o[8];
            #pragma unroll
            for (int j = 0; j < 8; ++j) {
                float v = __fadd_rn(accC[i][j], bb[j]);
                if (ACT == 1) v = fmaxf(v, 0.f);
                o[j] = v;
            }
            *reinterpret_cast<float4*>(&C[(size_t)row*Nn + bn + 4*tx])      = make_float4(o[0],o[1],o[2],o[3]);
            *reinterpret_cast<float4*>(&C[(size_t)row*Nn + bn + 64 + 4*tx]) = make_float4(o[4],o[5],o[6],o[7]);
        }
}

// ---------------------------------------------------------------------------
// bf16 helpers (RNE)
// ---------------------------------------------------------------------------
__device__ inline unsigned short bf16_rne(float x) {
    union { float f; unsigned u; } a; a.f = x;
    unsigned r = a.u + 0x7FFFu + ((a.u >> 16) & 1u);
    return (unsigned short)(r >> 16);
}

// W [K][N] fp32 -> WT [N][K] bf16 (plain cast, transposed for B-side rows)
__global__ __launch_bounds__(256) void convW_kernel(const float* __restrict__ W,
                                                    unsigned short* __restrict__ WT,
                                                    int K, int N)
{
    const int total = K * N;
    for (int t = blockIdx.x*256 + threadIdx.x; t < total; t += gridDim.x*256) {
        int k = t / N, n = t - k*N;
        WT[(size_t)n*K + k] = bf16_rne(W[(size_t)k*N + n]);
    }
}

// ---------------------------------------------------------------------------
// bf16 MFMA GEMM with FUSED fp32->bf16 A-cast (validated round 10 — UNCHANGED)
// ---------------------------------------------------------------------------
template<int ACT>
__global__ __launch_bounds__(256) void gemm_bf16_kernel(const float* __restrict__ A,
                                                        const unsigned short* __restrict__ BT,
                                                        const float* __restrict__ bias,
                                                        float* __restrict__ C,
                                                        int M, int K, int Nn)
{
    __shared__ unsigned short Asm[128*64];
    __shared__ unsigned short Bsm[128*64];
    const int tid  = threadIdx.x;
    const int lane = tid & 63;
    const int wave = tid >> 6;
    const int wr = wave >> 1, wc = wave & 1;
    const int bm = blockIdx.y * 128, bn = blockIdx.x * 128;
    const int l15 = lane & 15, l4 = lane >> 4;

    f32x4 acc[4][4];
    #pragma unroll
    for (int i = 0; i < 4; ++i)
        #pragma unroll
        for (int j = 0; j < 4; ++j) acc[i][j] = (f32x4){0.f,0.f,0.f,0.f};

    const int srow = tid >> 3;
    const int sch  = (tid & 7) * 8;
    for (int kt = 0; kt < K; kt += 64) {
        #pragma unroll
        for (int p = 0; p < 4; ++p) {
            int row = srow + 32*p;
            const float4 f0 = *reinterpret_cast<const float4*>(&A[(size_t)(bm+row)*K + kt + sch]);
            const float4 f1 = *reinterpret_cast<const float4*>(&A[(size_t)(bm+row)*K + kt + sch + 4]);
            short8 va;
            va[0] = (short)bf16_rne(f0.x); va[1] = (short)bf16_rne(f0.y);
            va[2] = (short)bf16_rne(f0.z); va[3] = (short)bf16_rne(f0.w);
            va[4] = (short)bf16_rne(f1.x); va[5] = (short)bf16_rne(f1.y);
            va[6] = (short)bf16_rne(f1.z); va[7] = (short)bf16_rne(f1.w);
            short8 vb = *reinterpret_cast<const short8*>(&BT[(size_t)(bn+row)*K + kt + sch]);
            int byte = (row*128 + sch*2) ^ ((row & 7) << 4);
            *reinterpret_cast<short8*>((char*)Asm + byte) = va;
            *reinterpret_cast<short8*>((char*)Bsm + byte) = vb;
        }
        __syncthreads();
        #pragma unroll
        for (int ks = 0; ks < 64; ks += 32) {
            const int kk2 = (ks + l4*8) * 2;
            short8 af[4], bf[4];
            #pragma unroll
            for (int i = 0; i < 4; ++i) {
                int mrow = wr*64 + i*16 + l15;
                af[i] = *reinterpret_cast<const short8*>((char*)Asm + ((mrow*128 + kk2) ^ ((mrow & 7) << 4)));
                int nrow = wc*64 + i*16 + l15;
                bf[i] = *reinterpret_cast<const short8*>((char*)Bsm + ((nrow*128 + kk2) ^ ((nrow & 7) << 4)));
            }
            #pragma unroll
            for (int i = 0; i < 4; ++i)
                #pragma unroll
                for (int j = 0; j < 4; ++j)
                    acc[i][j] = __builtin_amdgcn_mfma_f32_16x16x32_bf16(af[i], bf[j], acc[i][j], 0, 0, 0);
        }
        __syncthreads();
    }
    #pragma unroll
    for (int j = 0; j < 4; ++j) {
        const int col = bn + wc*64 + j*16 + l15;
        const float bv = bias[col];
        #pragma unroll
        for (int i = 0; i < 4; ++i) {
            #pragma unroll
            for (int r = 0; r < 4; ++r) {
                const int row = bm + wr*64 + i*16 + l4*4 + r;
                float v = acc[i][j][r] + bv;
                if (ACT == 1) v = fmaxf(v, 0.f);
                C[(size_t)row*Nn + col] = v;
            }
        }
    }
}

// ---------------------------------------------------------------------------
// numpy pairwise row-norm (validated bit-exact)
// ---------------------------------------------------------------------------
__global__ __launch_bounds__(128) void rownorm_np_kernel(const float* __restrict__ X,
                                                         int nrows,
                                                         float* __restrict__ out)
{
    const int r = blockIdx.x * 128 + threadIdx.x;
    if (r >= nrows) return;
    const float* p = X + (size_t)r * DIM;
    float lane[16];
    #pragma unroll
    for (int l = 0; l < 16; ++l) {
        float x0 = p[0*16 + l],  y0 = p[64 + 0*16 + l];
        float x1 = p[1*16 + l],  y1 = p[64 + 1*16 + l];
        float a0 = __fadd_rn(__fmul_rn(x0, x0), __fmul_rn(y0, y0));
        float a1 = __fadd_rn(__fmul_rn(x1, x1), __fmul_rn(y1, y1));
        float r01 = __fadd_rn(a0, a1);
        float x2 = p[2*16 + l],  y2 = p[64 + 2*16 + l];
        float x3 = p[3*16 + l],  y3 = p[64 + 3*16 + l];
        float a2 = __fadd_rn(__fmul_rn(x2, x2), __fmul_rn(y2, y2));
        float a3 = __fadd_rn(__fmul_rn(x3, x3), __fmul_rn(y3, y3));
        float r23 = __fadd_rn(a2, a3);
        lane[l] = __fadd_rn(r01, r23);
    }
    float s[8];
    #pragma unroll
    for (int l = 0; l < 8; ++l) s[l] = __fadd_rn(lane[l], lane[l+8]);
    float u[4];
    #pragma unroll
    for (int l = 0; l < 4; ++l) u[l] = __fadd_rn(s[l], s[l+4]);
    float v0 = __fadd_rn(u[0], u[2]);
    float v1 = __fadd_rn(u[1], u[3]);
    out[r] = __fadd_rn(v0, v1);
}

// ---------------------------------------------------------------------------
// Fused VQ — 8x8 micro at constant wave count: 512 threads (8 waves),
// 128 rows x 256 codes per tile, grid NROWS/128 = 256 blocks.
// Rows {4ty+r, 64+4ty+r} (ty in [0,16)); codes {4tx+j, 128+4tx+j} (tx in [0,32)).
// dist = fl( fl(SL+CN) - 2P ), P = sequential-d fmaf chain (bit-exact,
// validated); argmin shfl over 32-lane group, first-index tie-break.
// ---------------------------------------------------------------------------
__global__ __launch_bounds__(512, 2) void vq_kernel(const float* __restrict__ L,
                                                    const float* __restrict__ CB,
                                                    const float* __restrict__ SL,
                                                    const float* __restrict__ CN,
                                                    float* __restrict__ outInd,
                                                    float* __restrict__ outQ,
                                                    float* __restrict__ lossAcc)
{
    const int tid = threadIdx.x;
    const int tx = tid & 31, ty = tid >> 5;   // tx: 32 code-groups, ty: 16 row-groups
    const int bm = blockIdx.x * 128;

    __shared__ float As[32][132];   // [d][row 0..127]
    __shared__ float Bs[32][260];   // [d][code 0..255]
    __shared__ int   sIdx[128];

    float slr[8], bestv[8];
    int   besti[8];
    #pragma unroll
    for (int gr = 0; gr < 2; ++gr)
        #pragma unroll
        for (int r = 0; r < 4; ++r) {
            slr[gr*4+r] = SL[bm + 64*gr + 4*ty + r];
            bestv[gr*4+r] = 3.4e38f; besti[gr*4+r] = 0x7fffffff;
        }

    for (int k0 = 0; k0 < KCODE; k0 += 256) {
        float acc[8][8];
        #pragma unroll
        for (int r = 0; r < 8; ++r)
            #pragma unroll
            for (int j = 0; j < 8; ++j) acc[r][j] = 0.f;

        for (int d0 = 0; d0 < DIM; d0 += 32) {
            #pragma unroll
            for (int p = 0; p < 2; ++p) {
                int idx = tid + p*512;
                int row = idx >> 3;
                int d4  = (idx & 7) * 4;
                const float4 v = *reinterpret_cast<const float4*>(&L[(size_t)(bm+row)*DIM + d0 + d4]);
                As[d4+0][row] = v.x; As[d4+1][row] = v.y;
                As[d4+2][row] = v.z; As[d4+3][row] = v.w;
            }
            #pragma unroll
            for (int p = 0; p < 4; ++p) {
                int idx  = tid + p*512;
                int crow = idx >> 3;
                int d4   = (idx & 7) * 4;
                const float4 w = *reinterpret_cast<const float4*>(&CB[(size_t)(k0+crow)*DIM + d0 + d4]);
                Bs[d4+0][crow] = w.x; Bs[d4+1][crow] = w.y;
                Bs[d4+2][crow] = w.z; Bs[d4+3][crow] = w.w;
            }
            __syncthreads();
            #pragma unroll
            for (int dd = 0; dd < 32; ++dd) {
                const float4 a0 = *reinterpret_cast<const float4*>(&As[dd][4*ty]);
                const float4 a1 = *reinterpret_cast<const float4*>(&As[dd][4*ty + 64]);
                const float4 b0 = *reinterpret_cast<const float4*>(&Bs[dd][4*tx]);
                const float4 b1 = *reinterpret_cast<const float4*>(&Bs[dd][4*tx + 128]);
                const float aa[8] = {a0.x,a0.y,a0.z,a0.w,a1.x,a1.y,a1.z,a1.w};
                const float bb[8] = {b0.x,b0.y,b0.z,b0.w,b1.x,b1.y,b1.z,b1.w};
                #pragma unroll
                for (int r = 0; r < 8; ++r)
                    #pragma unroll
                    for (int j = 0; j < 8; ++j)
                        acc[r][j] = fmaf(aa[r], bb[j], acc[r][j]);
            }
            __syncthreads();
        }
        #pragma unroll
        for (int r = 0; r < 8; ++r) {
            float mv = 3.4e38f; int mi = 0x7fffffff;
            #pragma unroll
            for (int j = 0; j < 8; ++j) {
                int c = k0 + ((j < 4) ? (4*tx + j) : (128 + 4*tx + (j-4)));
                float t1   = __fadd_rn(slr[r], CN[c]);      // fl(SL + CN)
                float u    = __fmul_rn(2.0f, acc[r][j]);    // exact
                float dist = __fadd_rn(t1, -u);             // fl(t1 - 2P)
                if (dist < mv || (dist == mv && c < mi)) { mv = dist; mi = c; }
            }
            // reduce across the 32 tx lanes (masks stay within 32-lane group)
            #pragma unroll
            for (int m = 1; m < 32; m <<= 1) {
                float ov = __shfl_xor(mv, m, 32);
                int   oi = __shfl_xor(mi, m, 32);
                if (ov < mv || (ov == mv && oi < mi)) { mv = ov; mi = oi; }
            }
            if (mv < bestv[r] || (mv == bestv[r] && mi < besti[r])) {
                bestv[r] = mv; besti[r] = mi;
            }
        }
    }
    if (tx == 0) {
        #pragma unroll
        for (int gr = 0; gr < 2; ++gr)
            #pragma unroll
            for (int r = 0; r < 4; ++r) {
                int row = 64*gr + 4*ty + r;
                outInd[bm + row] = (float)besti[gr*4+r];
                sIdx[row] = besti[gr*4+r];
            }
    }
    __syncthreads();
    float lsum = 0.f;
    #pragma unroll
    for (int p = 0; p < 8; ++p) {
        int q   = tid + p*512;
        int row = q >> 5;
        int d4  = (q & 31) * 4;
        int ci  = sIdx[row];
        const float4 qv = *reinterpret_cast<const float4*>(&CB[(size_t)ci*DIM + d4]);
        const float4 lv = *reinterpret_cast<const float4*>(&L[(size_t)(bm+row)*DIM + d4]);
        *reinterpret_cast<float4*>(&outQ[(size_t)(bm+row)*DIM + d4]) = qv;
        float dx = qv.x - lv.x, dy = qv.y - lv.y, dz = qv.z - lv.z, dw = qv.w - lv.w;
        lsum += dx*dx + dy*dy + dz*dz + dw*dw;
    }
    #pragma unroll
    for (int s = 32; s; s >>= 1) lsum += __shfl_down(lsum, s, 64);
    __shared__ float part[8];
    if ((tid & 63) == 0) part[tid >> 6] = lsum;
    __syncthreads();
    if (tid == 0) {
        float t = 0.f;
        #pragma unroll
        for (int w = 0; w < 8; ++w) t += part[w];
        atomicAdd(lossAcc, t);
    }
}

// ---------------------------------------------------------------------------
// Decoder layer 3: tanh head — wave per row (validated)
// ---------------------------------------------------------------------------
__global__ __launch_bounds__(256) void dec3_kernel(const float* __restrict__ d2,
                                                   const float* __restrict__ Wd3,
                                                   const float* __restrict__ bd3,
                                                   float* __restrict__ out)
{
    const int w = threadIdx.x >> 6, lane = threadIdx.x & 63;
    const int n = blockIdx.x * 4 + w;
    float acc[6] = {0.f, 0.f, 0.f, 0.f, 0.f, 0.f};
    for (int k = lane; k < HID; k += 64) {
        float v = d2[(size_t)n*HID + k];
        #pragma unroll
        for (int o = 0; o < 6; ++o) acc[o] = fmaf(v, Wd3[k*6 + o], acc[o]);
    }
    #pragma unroll
    for (int o = 0; o < 6; ++o)
        #pragma unroll
        for (int s = 32; s; s >>= 1) acc[o] += __shfl_down(acc[o], s, 64);
    if (lane == 0) {
        #pragma unroll
        for (int o = 0; o < 6; ++o)
            out[(size_t)n*6 + o] = tanhf(__fadd_rn(acc[o], bd3[o]));
    }
}

__global__ void zero1_kernel(float* __restrict__ p) { p[0] = 0.f; }

__global__ void loss_final_kernel(const float* __restrict__ lossAcc,
                                  float* __restrict__ out)
{
    out[0] = 1.25f * lossAcc[0] / (float)(NROWS * DIM);
}

// ---------------------------------------------------------------------------
extern "C" void kernel_launch(void* const* d_in, const int* in_sizes, int n_in,
                              void* d_out, int out_size, void* d_ws, size_t ws_size,
                              hipStream_t stream)
{
    const float* action = (const float*)d_in[0];
    const float* W1  = (const float*)d_in[1];
    const float* b1  = (const float*)d_in[2];
    const float* W2  = (const float*)d_in[3];
    const float* b2  = (const float*)d_in[4];
    const float* Wmu = (const float*)d_in[5];
    const float* bmu = (const float*)d_in[6];
    const float* CB  = (const float*)d_in[7];
    const float* Wd1 = (const float*)d_in[8];
    const float* bd1 = (const float*)d_in[9];
    const float* Wd2 = (const float*)d_in[10];
    const float* bd2 = (const float*)d_in[11];
    const float* Wd3 = (const float*)d_in[12];
    const float* bd3 = (const float*)d_in[13];

    float* out = (float*)d_out;
    const size_t o1 = NROWS;
    const size_t o2 = o1 + (size_t)NROWS*DIM;
    const size_t o3 = o2 + (size_t)NROWS*6;

    int ch = 8192;
    size_t need = 0;
    while (true) {
        need = 2*(size_t)ch*HID*4 + (size_t)NROWS*DIM*4 + (size_t)NROWS*4
             + (size_t)KCODE*4 + 64
             + (size_t)HID*DIM*2 + (size_t)HID*HID*2;
        if (need <= ws_size || ch <= 128) break;
        ch >>= 1;
    }
    if (need > ws_size) return;

    char* ws = (char*)d_ws;
    size_t off = 0;
    float* bufA    = (float*)(ws + off); off += (size_t)ch*HID*4;
    float* bufB    = (float*)(ws + off); off += (size_t)ch*HID*4;
    float* latF    = (float*)(ws + off); off += (size_t)NROWS*DIM*4;
    float* slF     = (float*)(ws + off); off += (size_t)NROWS*4;
    float* cnorm   = (float*)(ws + off); off += (size_t)KCODE*4;
    float* lossAcc = (float*)(ws + off); off += 64;
    unsigned short* W1T = (unsigned short*)(ws + off); off += (size_t)HID*DIM*2;
    unsigned short* W2T = (unsigned short*)(ws + off);

    zero1_kernel<<<1, 1, 0, stream>>>(lossAcc);
    rownorm_np_kernel<<<dim3(KCODE/128), 128, 0, stream>>>(CB, KCODE, cnorm);
    convW_kernel<<<dim3(256), 256, 0, stream>>>(Wd1, W1T, DIM, HID);
    convW_kernel<<<dim3(1024), 256, 0, stream>>>(Wd2, W2T, HID, HID);

    // ---- encoder (chunked, bit-exact fp32) -> full latents
    for (int c0 = 0; c0 < NROWS; c0 += ch) {
        enc1_kernel<<<dim3(HID/256, ch), 256, 0, stream>>>(action + (size_t)c0*6, W1, b1, bufA);
        gemm_kernel<128,1><<<dim3(HID/128, ch/128), 256, 0, stream>>>(bufA, W2, b2, bufB, ch, HID, HID);
        gemm_kernel<64,0><<<dim3(1, ch/64), 256, 0, stream>>>(bufB, Wmu, bmu, latF + (size_t)c0*DIM, ch, HID, DIM);
    }

    // ---- VQ (bit-exact fp32, full N, 256 blocks x 8 waves)
    rownorm_np_kernel<<<dim3(NROWS/128), 128, 0, stream>>>(latF, NROWS, slF);
    vq_kernel<<<dim3(NROWS/128), 512, 0, stream>>>(latF, CB, slF, cnorm, out, out + o1, lossAcc);

    // ---- decoder (chunked, plain-bf16 MFMA with fused A-cast)
    for (int c0 = 0; c0 < NROWS; c0 += ch) {
        const float* qC = out + o1 + (size_t)c0*DIM;
        gemm_bf16_kernel<1><<<dim3(HID/128, ch/128), 256, 0, stream>>>(qC, W1T, bd1, bufA, ch, DIM, HID);
        gemm_bf16_kernel<1><<<dim3(HID/128, ch/128), 256, 0, stream>>>(bufA, W2T, bd2, bufB, ch, HID, HID);
        dec3_kernel<<<dim3(ch/4), 256, 0, stream>>>(bufB, Wd3, bd3, out + o2 + (size_t)c0*6);
    }

    loss_final_kernel<<<1, 1, 0, stream>>>(lossAcc, out + o3);
}